// Round 1
// baseline (1811.223 us; speedup 1.0000x reference)
//
#include <hip/hip_runtime.h>
#include <math.h>

// Graph normalizing flow on MI355X.
// State x (N x 128) lives in d_out; ldj at d_out[N*128].
// Propagation uses CSR-by-destination (gather, no float atomics).
// Rewrite A(hW)=(Ah)W so s/t GCN layer-0 share one 64-feat propagation.

__global__ void init_out_kernel(const float* __restrict__ x, float* __restrict__ out, int total) {
  int i = blockIdx.x * blockDim.x + threadIdx.x;
  if (i < total) out[i] = x[i];
  if (i == 0) out[total] = 0.f;  // ldj accumulator
}

__global__ void meta_init_kernel(int* cnt, int* fill, int n) {
  int i = blockIdx.x * blockDim.x + threadIdx.x;
  if (i < n) { cnt[i] = 1; fill[i] = 0; }  // cnt starts at 1: self-loop
}

__global__ void count_kernel(const int* __restrict__ dst, int* cnt, int e) {
  int i = blockIdx.x * blockDim.x + threadIdx.x;
  if (i < e) atomicAdd(&cnt[dst[i]], 1);
}

__global__ void dinv_kernel(const int* __restrict__ cnt, float* __restrict__ dinv, int n) {
  int i = blockIdx.x * blockDim.x + threadIdx.x;
  if (i < n) dinv[i] = rsqrtf(fmaxf((float)cnt[i], 1.f));
}

// Single-block exclusive scan over cnt -> row_ptr (N=50000 is tiny; ~µs).
__global__ void scan_kernel(const int* __restrict__ cnt, int* __restrict__ row_ptr, int n, int m) {
  __shared__ int sdata[1024];
  __shared__ int s_off;
  int tid = threadIdx.x;
  if (tid == 0) s_off = 0;
  __syncthreads();
  for (int base = 0; base < n; base += 1024) {
    int i = base + tid;
    int v = (i < n) ? cnt[i] : 0;
    sdata[tid] = v;
    __syncthreads();
    for (int d = 1; d < 1024; d <<= 1) {
      int t = (tid >= d) ? sdata[tid - d] : 0;
      __syncthreads();
      sdata[tid] += t;
      __syncthreads();
    }
    if (i < n) row_ptr[i] = s_off + sdata[tid] - v;
    __syncthreads();
    if (tid == 1023) s_off += sdata[1023];
    __syncthreads();
  }
  if (tid == 0) row_ptr[n] = m;
}

__global__ void fill_kernel(const int* __restrict__ src, const int* __restrict__ dst,
                            const float* __restrict__ dinv, const int* __restrict__ row_ptr,
                            int* fill, int* __restrict__ col, float* __restrict__ wgt,
                            int e, int n) {
  int i = blockIdx.x * blockDim.x + threadIdx.x;
  if (i < e) {
    int s = src[i], d = dst[i];
    int pos = row_ptr[d] + atomicAdd(&fill[d], 1);
    col[pos] = s;
    wgt[pos] = dinv[s] * dinv[d];
  } else if (i < e + n) {
    int v = i - e;
    int pos = row_ptr[v] + atomicAdd(&fill[v], 1);
    col[pos] = v;
    float dv = dinv[v];
    wgt[pos] = dv * dv;
  }
}

// Y[node][f] = sum_{edges into node} w * X[col][xoff+f].  One wave covers 64 feats.
template <int F>
__global__ void propagate_kernel(const float* __restrict__ X, int ldx, int xoff,
                                 float* __restrict__ Y,
                                 const int* __restrict__ row_ptr, const int* __restrict__ col,
                                 const float* __restrict__ wgt, int n) {
  int t = blockIdx.x * blockDim.x + threadIdx.x;
  int node = t / F;
  int f = t % F;
  if (node >= n) return;
  int beg = row_ptr[node], end = row_ptr[node + 1];
  float acc = 0.f;
  for (int i = beg; i < end; ++i) {
    int c = col[i];
    float w = wgt[i];
    acc += w * X[(size_t)c * ldx + xoff + f];
  }
  Y[(size_t)node * F + f] = acc;
}

// h1[n][0:64]  = relu(p[n] @ W[gs][0] + b[gs][0])
// h1[n][64:128]= relu(p[n] @ W[gt][0] + b[gt][0])
__global__ void layer0_kernel(const float* __restrict__ P, const float* __restrict__ W,
                              const float* __restrict__ B, int gs, int gt,
                              float* __restrict__ H1, int n) {
  __shared__ float wT[128][65];  // wT[j][k] = W[k][j]; +1 pad -> conflict-free
  __shared__ float bsh[128];
  for (int idx = threadIdx.x; idx < 8192; idx += blockDim.x) {
    int j = idx >> 6, k = idx & 63;
    int g = (j < 64) ? gs : gt;
    wT[j][k] = W[(size_t)(g * 2 + 0) * 4096 + k * 64 + (j & 63)];
  }
  if (threadIdx.x < 128) {
    int j = threadIdx.x;
    int g = (j < 64) ? gs : gt;
    bsh[j] = B[(g * 2 + 0) * 64 + (j & 63)];
  }
  __syncthreads();
  int nodeBase = blockIdx.x * 32;
  for (int rep = 0; rep < 16; ++rep) {
    int node = nodeBase + rep * 2 + (threadIdx.x >> 7);
    int j = threadIdx.x & 127;
    if (node < n) {
      const float* prow = P + (size_t)node * 64;
      float acc = bsh[j];
#pragma unroll
      for (int k = 0; k < 64; ++k) acc += prow[k] * wT[j][k];
      H1[(size_t)node * 128 + j] = fmaxf(acc, 0.f);
    }
  }
}

// s = sigmoid(q[:, :64] @ W[gs][1] + b), t = sigmoid(q[:, 64:] @ W[gt][1] + b)
// xout = xout*exp(s)+t ; ldj += sum(s)
__global__ void final_kernel(const float* __restrict__ Q, const float* __restrict__ W,
                             const float* __restrict__ B, int gs, int gt,
                             float* __restrict__ Xout, int xoff, float* __restrict__ ldj, int n) {
  __shared__ float wsT[64][65];
  __shared__ float wtT[64][65];
  __shared__ float bsv[64], btv[64];
  for (int idx = threadIdx.x; idx < 4096; idx += blockDim.x) {
    int j = idx >> 6, k = idx & 63;
    wsT[j][k] = W[(size_t)(gs * 2 + 1) * 4096 + k * 64 + j];
    wtT[j][k] = W[(size_t)(gt * 2 + 1) * 4096 + k * 64 + j];
  }
  if (threadIdx.x < 64) {
    bsv[threadIdx.x] = B[(gs * 2 + 1) * 64 + threadIdx.x];
    btv[threadIdx.x] = B[(gt * 2 + 1) * 64 + threadIdx.x];
  }
  __syncthreads();
  int nodeBase = blockIdx.x * 64;
  float wldj = 0.f;
  for (int rep = 0; rep < 16; ++rep) {
    int node = nodeBase + rep * 4 + (threadIdx.x >> 6);
    int j = threadIdx.x & 63;
    if (node < n) {
      const float* qrow = Q + (size_t)node * 128;
      float sa = bsv[j], ta = btv[j];
#pragma unroll
      for (int k = 0; k < 64; ++k) {
        sa += qrow[k] * wsT[j][k];
        ta += qrow[64 + k] * wtT[j][k];
      }
      float sv = 1.f / (1.f + __expf(-sa));
      float tv = 1.f / (1.f + __expf(-ta));
      size_t o = (size_t)node * 128 + xoff + j;
      Xout[o] = Xout[o] * __expf(sv) + tv;
      wldj += sv;
    }
  }
  for (int off = 32; off > 0; off >>= 1) wldj += __shfl_down(wldj, off);
  if ((threadIdx.x & 63) == 0) atomicAdd(ldj, wldj);
}

extern "C" void kernel_launch(void* const* d_in, const int* in_sizes, int n_in,
                              void* d_out, int out_size, void* d_ws, size_t ws_size,
                              hipStream_t stream) {
  const float* x = (const float*)d_in[0];
  const int* eidx = (const int*)d_in[1];
  const float* W = (const float*)d_in[2];
  const float* B = (const float*)d_in[3];
  float* out = (float*)d_out;

  int n = in_sizes[0] / 128;
  int e = in_sizes[1] / 2;
  int m = e + n;
  const int* src = eidx;
  const int* dstv = eidx + e;

  size_t off = 0;
  auto alloc = [&](size_t bytes) {
    size_t r = off;
    off += (bytes + 255) & ~(size_t)255;
    return r;
  };
  char* ws = (char*)d_ws;
  int* cnt = (int*)(ws + alloc((size_t)n * 4));
  int* fill = (int*)(ws + alloc((size_t)n * 4));
  int* row_ptr = (int*)(ws + alloc((size_t)(n + 1) * 4));
  float* dinv = (float*)(ws + alloc((size_t)n * 4));
  int* col = (int*)(ws + alloc((size_t)m * 4));
  float* wgt = (float*)(ws + alloc((size_t)m * 4));
  float* p = (float*)(ws + alloc((size_t)n * 64 * 4));
  float* h1 = (float*)(ws + alloc((size_t)n * 128 * 4));
  float* q = (float*)(ws + alloc((size_t)n * 128 * 4));

  int total = n * 128;
  init_out_kernel<<<(total + 256) / 256, 256, 0, stream>>>(x, out, total);
  meta_init_kernel<<<(n + 255) / 256, 256, 0, stream>>>(cnt, fill, n);
  count_kernel<<<(e + 255) / 256, 256, 0, stream>>>(dstv, cnt, e);
  dinv_kernel<<<(n + 255) / 256, 256, 0, stream>>>(cnt, dinv, n);
  scan_kernel<<<1, 1024, 0, stream>>>(cnt, row_ptr, n, m);
  fill_kernel<<<(m + 255) / 256, 256, 0, stream>>>(src, dstv, dinv, row_ptr, fill, col, wgt, e, n);

  float* ldj = out + total;
  // half-steps: (xin offset, gnn-ids for s and t); xout = other half
  const int hs_xin[4] = {0, 64, 0, 64};
  const int hs_gs[4] = {0, 4, 1, 5};
  const int hs_gt[4] = {2, 6, 3, 7};
  for (int hsi = 0; hsi < 4; ++hsi) {
    int xin = hs_xin[hsi];
    int xout = 64 - xin;
    propagate_kernel<64><<<(n * 64 + 255) / 256, 256, 0, stream>>>(out, 128, xin, p, row_ptr, col, wgt, n);
    layer0_kernel<<<(n + 31) / 32, 256, 0, stream>>>(p, W, B, hs_gs[hsi], hs_gt[hsi], h1, n);
    propagate_kernel<128><<<(n * 128 + 255) / 256, 256, 0, stream>>>(h1, 128, 0, q, row_ptr, col, wgt, n);
    final_kernel<<<(n + 63) / 64, 256, 0, stream>>>(q, W, B, hs_gs[hsi], hs_gt[hsi], out, xout, ldj, n);
  }
}

// Round 2
// 1156.983 us; speedup vs baseline: 1.5655x; 1.5655x over previous
//
#include <hip/hip_runtime.h>
#include <math.h>

// Graph normalizing flow on MI355X.
// State x (N x 128) fp32 lives in d_out; bf16 mirror xb for propagation gathers.
// ldj at d_out[N*128]. CSR-by-destination gather (no float atomics in hot path).
// Rewrite A(hW)=(Ah)W so s/t GCN layer-0 share one 64-feat propagation.

__device__ __forceinline__ float bf_lo(unsigned int u) { return __uint_as_float(u << 16); }
__device__ __forceinline__ float bf_hi(unsigned int u) { return __uint_as_float(u & 0xffff0000u); }
__device__ __forceinline__ unsigned short f2bf(float f) {
  unsigned int u = __float_as_uint(f);
  u = (u + 0x7fffu + ((u >> 16) & 1u)) >> 16;  // round-to-nearest-even
  return (unsigned short)u;
}

__global__ void init_out_kernel(const float* __restrict__ x, float* __restrict__ out,
                                unsigned short* __restrict__ xb, int total) {
  int i = blockIdx.x * blockDim.x + threadIdx.x;
  if (i < total) {
    float v = x[i];
    out[i] = v;
    xb[i] = f2bf(v);
  }
  if (i == 0) out[total] = 0.f;  // ldj accumulator
}

__global__ void meta_init_kernel(int* cnt, int* fill, int n) {
  int i = blockIdx.x * blockDim.x + threadIdx.x;
  if (i < n) { cnt[i] = 1; fill[i] = 0; }  // cnt starts at 1: self-loop
}

__global__ void count_kernel(const int* __restrict__ dst, int* cnt, int e) {
  int i = blockIdx.x * blockDim.x + threadIdx.x;
  if (i < e) atomicAdd(&cnt[dst[i]], 1);
}

__global__ void dinv_kernel(const int* __restrict__ cnt, float* __restrict__ dinv, int n) {
  int i = blockIdx.x * blockDim.x + threadIdx.x;
  if (i < n) dinv[i] = rsqrtf(fmaxf((float)cnt[i], 1.f));
}

// Single-block exclusive scan over cnt -> row_ptr (N=50000 is tiny).
__global__ void scan_kernel(const int* __restrict__ cnt, int* __restrict__ row_ptr, int n, int m) {
  __shared__ int sdata[1024];
  __shared__ int s_off;
  int tid = threadIdx.x;
  if (tid == 0) s_off = 0;
  __syncthreads();
  for (int base = 0; base < n; base += 1024) {
    int i = base + tid;
    int v = (i < n) ? cnt[i] : 0;
    sdata[tid] = v;
    __syncthreads();
    for (int d = 1; d < 1024; d <<= 1) {
      int t = (tid >= d) ? sdata[tid - d] : 0;
      __syncthreads();
      sdata[tid] += t;
      __syncthreads();
    }
    if (i < n) row_ptr[i] = s_off + sdata[tid] - v;
    __syncthreads();
    if (tid == 1023) s_off += sdata[1023];
    __syncthreads();
  }
  if (tid == 0) row_ptr[n] = m;
}

__global__ void fill_kernel(const int* __restrict__ src, const int* __restrict__ dst,
                            const float* __restrict__ dinv, const int* __restrict__ row_ptr,
                            int* fill, int* __restrict__ col, float* __restrict__ wgt,
                            int e, int n) {
  int i = blockIdx.x * blockDim.x + threadIdx.x;
  if (i < e) {
    int s = src[i], d = dst[i];
    int pos = row_ptr[d] + atomicAdd(&fill[d], 1);
    col[pos] = s;
    wgt[pos] = dinv[s] * dinv[d];
  } else if (i < e + n) {
    int v = i - e;
    int pos = row_ptr[v] + atomicAdd(&fill[v], 1);
    col[pos] = v;
    float dv = dinv[v];
    wgt[pos] = dv * dv;
  }
}

// Y[node][2*lo:2*lo+2] = sum_{edges into node} w * bf16(X[col])[...]
// LPN lanes per node, each lane owns a feature PAIR (one uint = 2 bf16).
// 4-way unrolled: 4 independent row gathers in flight per thread.
template <int LPN>
__global__ void propagate_kernel(const unsigned int* __restrict__ X, int ldu, int xoffu,
                                 float* __restrict__ Y, int ldy,
                                 const int* __restrict__ row_ptr, const int* __restrict__ col,
                                 const float* __restrict__ wgt, int n) {
  int t = blockIdx.x * blockDim.x + threadIdx.x;
  int node = t / LPN;
  int lo = t % LPN;
  if (node >= n) return;
  int beg = row_ptr[node], end = row_ptr[node + 1];
  const unsigned int* __restrict__ Xl = X + xoffu + lo;
  float a0 = 0.f, a1 = 0.f;
  int i = beg;
  for (; i + 4 <= end; i += 4) {
    int c0 = col[i], c1 = col[i + 1], c2 = col[i + 2], c3 = col[i + 3];
    float w0 = wgt[i], w1 = wgt[i + 1], w2 = wgt[i + 2], w3 = wgt[i + 3];
    unsigned int u0 = Xl[(size_t)c0 * ldu];
    unsigned int u1 = Xl[(size_t)c1 * ldu];
    unsigned int u2 = Xl[(size_t)c2 * ldu];
    unsigned int u3 = Xl[(size_t)c3 * ldu];
    a0 += w0 * bf_lo(u0); a1 += w0 * bf_hi(u0);
    a0 += w1 * bf_lo(u1); a1 += w1 * bf_hi(u1);
    a0 += w2 * bf_lo(u2); a1 += w2 * bf_hi(u2);
    a0 += w3 * bf_lo(u3); a1 += w3 * bf_hi(u3);
  }
  for (; i < end; ++i) {
    int c = col[i];
    float w = wgt[i];
    unsigned int u = Xl[(size_t)c * ldu];
    a0 += w * bf_lo(u); a1 += w * bf_hi(u);
  }
  float2* __restrict__ yrow = (float2*)(Y + (size_t)node * ldy);
  yrow[lo] = make_float2(a0, a1);
}

// h1[n][0:64]  = bf16(relu(p[n] @ W[gs][0] + b[gs][0]))
// h1[n][64:128]= bf16(relu(p[n] @ W[gt][0] + b[gt][0]))
__global__ void layer0_kernel(const float* __restrict__ P, const float* __restrict__ W,
                              const float* __restrict__ B, int gs, int gt,
                              unsigned short* __restrict__ H1, int n) {
  __shared__ float wT[128][65];  // wT[j][k] = W[k][j]; +1 pad -> conflict-free
  __shared__ float bsh[128];
  for (int idx = threadIdx.x; idx < 8192; idx += blockDim.x) {
    int j = idx >> 6, k = idx & 63;
    int g = (j < 64) ? gs : gt;
    wT[j][k] = W[(size_t)(g * 2 + 0) * 4096 + k * 64 + (j & 63)];
  }
  if (threadIdx.x < 128) {
    int j = threadIdx.x;
    int g = (j < 64) ? gs : gt;
    bsh[j] = B[(g * 2 + 0) * 64 + (j & 63)];
  }
  __syncthreads();
  int nodeBase = blockIdx.x * 32;
  for (int rep = 0; rep < 16; ++rep) {
    int node = nodeBase + rep * 2 + (threadIdx.x >> 7);
    int j = threadIdx.x & 127;
    if (node < n) {
      const float* prow = P + (size_t)node * 64;
      float acc = bsh[j];
#pragma unroll
      for (int k = 0; k < 64; ++k) acc += prow[k] * wT[j][k];
      H1[(size_t)node * 128 + j] = f2bf(fmaxf(acc, 0.f));
    }
  }
}

// s = sigmoid(q[:, :64] @ W[gs][1] + b), t = sigmoid(q[:, 64:] @ W[gt][1] + b)
// xout = xout*exp(s)+t (fp32), bf16 mirror updated; ldj += sum(s)
__global__ void final_kernel(const float* __restrict__ Q, const float* __restrict__ W,
                             const float* __restrict__ B, int gs, int gt,
                             float* __restrict__ Xout, unsigned short* __restrict__ Xb,
                             int xoff, float* __restrict__ ldj, int n) {
  __shared__ float wsT[64][65];
  __shared__ float wtT[64][65];
  __shared__ float bsv[64], btv[64];
  for (int idx = threadIdx.x; idx < 4096; idx += blockDim.x) {
    int j = idx >> 6, k = idx & 63;
    wsT[j][k] = W[(size_t)(gs * 2 + 1) * 4096 + k * 64 + j];
    wtT[j][k] = W[(size_t)(gt * 2 + 1) * 4096 + k * 64 + j];
  }
  if (threadIdx.x < 64) {
    bsv[threadIdx.x] = B[(gs * 2 + 1) * 64 + threadIdx.x];
    btv[threadIdx.x] = B[(gt * 2 + 1) * 64 + threadIdx.x];
  }
  __syncthreads();
  int nodeBase = blockIdx.x * 64;
  float wldj = 0.f;
  for (int rep = 0; rep < 16; ++rep) {
    int node = nodeBase + rep * 4 + (threadIdx.x >> 6);
    int j = threadIdx.x & 63;
    if (node < n) {
      const float* qrow = Q + (size_t)node * 128;
      float sa = bsv[j], ta = btv[j];
#pragma unroll
      for (int k = 0; k < 64; ++k) {
        sa += qrow[k] * wsT[j][k];
        ta += qrow[64 + k] * wtT[j][k];
      }
      float sv = 1.f / (1.f + __expf(-sa));
      float tv = 1.f / (1.f + __expf(-ta));
      size_t o = (size_t)node * 128 + xoff + j;
      float nv = Xout[o] * __expf(sv) + tv;
      Xout[o] = nv;
      Xb[o] = f2bf(nv);
      wldj += sv;
    }
  }
  for (int off = 32; off > 0; off >>= 1) wldj += __shfl_down(wldj, off);
  if ((threadIdx.x & 63) == 0) atomicAdd(ldj, wldj);
}

extern "C" void kernel_launch(void* const* d_in, const int* in_sizes, int n_in,
                              void* d_out, int out_size, void* d_ws, size_t ws_size,
                              hipStream_t stream) {
  const float* x = (const float*)d_in[0];
  const int* eidx = (const int*)d_in[1];
  const float* W = (const float*)d_in[2];
  const float* B = (const float*)d_in[3];
  float* out = (float*)d_out;

  int n = in_sizes[0] / 128;
  int e = in_sizes[1] / 2;
  int m = e + n;
  const int* src = eidx;
  const int* dstv = eidx + e;

  size_t off = 0;
  auto alloc = [&](size_t bytes) {
    size_t r = off;
    off += (bytes + 255) & ~(size_t)255;
    return r;
  };
  char* ws = (char*)d_ws;
  int* cnt = (int*)(ws + alloc((size_t)n * 4));
  int* fill = (int*)(ws + alloc((size_t)n * 4));
  int* row_ptr = (int*)(ws + alloc((size_t)(n + 1) * 4));
  float* dinv = (float*)(ws + alloc((size_t)n * 4));
  int* col = (int*)(ws + alloc((size_t)m * 4));
  float* wgt = (float*)(ws + alloc((size_t)m * 4));
  float* p = (float*)(ws + alloc((size_t)n * 64 * 4));            // fp32 A*x_in
  unsigned short* h1 = (unsigned short*)(ws + alloc((size_t)n * 128 * 2));  // bf16 hidden
  float* q = (float*)(ws + alloc((size_t)n * 128 * 4));           // fp32 A*h1
  unsigned short* xb = (unsigned short*)(ws + alloc((size_t)n * 128 * 2)); // bf16 state mirror

  int total = n * 128;
  init_out_kernel<<<(total + 256) / 256, 256, 0, stream>>>(x, out, xb, total);
  meta_init_kernel<<<(n + 255) / 256, 256, 0, stream>>>(cnt, fill, n);
  count_kernel<<<(e + 255) / 256, 256, 0, stream>>>(dstv, cnt, e);
  dinv_kernel<<<(n + 255) / 256, 256, 0, stream>>>(cnt, dinv, n);
  scan_kernel<<<1, 1024, 0, stream>>>(cnt, row_ptr, n, m);
  fill_kernel<<<(m + 255) / 256, 256, 0, stream>>>(src, dstv, dinv, row_ptr, fill, col, wgt, e, n);

  float* ldj = out + total;
  // half-steps: (xin offset, gnn-ids for s and t); xout = other half
  const int hs_xin[4] = {0, 64, 0, 64};
  const int hs_gs[4] = {0, 4, 1, 5};
  const int hs_gt[4] = {2, 6, 3, 7};
  for (int hsi = 0; hsi < 4; ++hsi) {
    int xin = hs_xin[hsi];
    int xout = 64 - xin;
    // p = A * x_in  (64 feats; xb is n x 64 uints, offset xin/2 uints)
    propagate_kernel<32><<<(n * 32 + 255) / 256, 256, 0, stream>>>(
        (const unsigned int*)xb, 64, xin / 2, p, 64, row_ptr, col, wgt, n);
    layer0_kernel<<<(n + 31) / 32, 256, 0, stream>>>(p, W, B, hs_gs[hsi], hs_gt[hsi], h1, n);
    // q = A * h1  (128 feats; h1 is n x 64 uints)
    propagate_kernel<64><<<(n * 64 + 255) / 256, 256, 0, stream>>>(
        (const unsigned int*)h1, 64, 0, q, 128, row_ptr, col, wgt, n);
    final_kernel<<<(n + 63) / 64, 256, 0, stream>>>(q, W, B, hs_gs[hsi], hs_gt[hsi], out, xb, xout, ldj, n);
  }
}

// Round 3
// 652.896 us; speedup vs baseline: 2.7741x; 1.7721x over previous
//
#include <hip/hip_runtime.h>
#include <math.h>

// Graph normalizing flow on MI355X.
// State x (N x 128) fp32 lives in d_out; bf16 mirror xb for propagation gathers.
// ldj at d_out[N*128]. CSR-by-destination gather (no float atomics in hot path).
// A(hW)=(Ah)W rewrite: s/t GCN layer-0 share one 64-feat propagation.
// Dense layers are bf16 MFMA GEMMs with fused epilogues.

typedef __attribute__((ext_vector_type(8))) short bf16x8;
typedef __attribute__((ext_vector_type(4))) float f32x4;

__device__ __forceinline__ float bf_lo(unsigned int u) { return __uint_as_float(u << 16); }
__device__ __forceinline__ float bf_hi(unsigned int u) { return __uint_as_float(u & 0xffff0000u); }
__device__ __forceinline__ unsigned short f2bf(float f) {
  unsigned int u = __float_as_uint(f);
  u = (u + 0x7fffu + ((u >> 16) & 1u)) >> 16;  // round-to-nearest-even
  return (unsigned short)u;
}
__device__ __forceinline__ unsigned int pack2(float a, float b) {
  return (unsigned int)f2bf(a) | ((unsigned int)f2bf(b) << 16);
}

__global__ void init_out_kernel(const float* __restrict__ x, float* __restrict__ out,
                                unsigned short* __restrict__ xb, int total) {
  int i = blockIdx.x * blockDim.x + threadIdx.x;
  if (i < total) {
    float v = x[i];
    out[i] = v;
    xb[i] = f2bf(v);
  }
  if (i == 0) out[total] = 0.f;  // ldj accumulator
}

__global__ void meta_init_kernel(int* cnt, int* fill, int n) {
  int i = blockIdx.x * blockDim.x + threadIdx.x;
  if (i < n) { cnt[i] = 1; fill[i] = 0; }  // cnt starts at 1: self-loop
}

__global__ void count_kernel(const int* __restrict__ dst, int* cnt, int e) {
  int i = blockIdx.x * blockDim.x + threadIdx.x;
  if (i < e) atomicAdd(&cnt[dst[i]], 1);
}

__global__ void dinv_kernel(const int* __restrict__ cnt, float* __restrict__ dinv, int n) {
  int i = blockIdx.x * blockDim.x + threadIdx.x;
  if (i < n) dinv[i] = rsqrtf(fmaxf((float)cnt[i], 1.f));
}

// Single-block exclusive scan over cnt -> row_ptr (N=50000 is tiny).
__global__ void scan_kernel(const int* __restrict__ cnt, int* __restrict__ row_ptr, int n, int m) {
  __shared__ int sdata[1024];
  __shared__ int s_off;
  int tid = threadIdx.x;
  if (tid == 0) s_off = 0;
  __syncthreads();
  for (int base = 0; base < n; base += 1024) {
    int i = base + tid;
    int v = (i < n) ? cnt[i] : 0;
    sdata[tid] = v;
    __syncthreads();
    for (int d = 1; d < 1024; d <<= 1) {
      int t = (tid >= d) ? sdata[tid - d] : 0;
      __syncthreads();
      sdata[tid] += t;
      __syncthreads();
    }
    if (i < n) row_ptr[i] = s_off + sdata[tid] - v;
    __syncthreads();
    if (tid == 1023) s_off += sdata[1023];
    __syncthreads();
  }
  if (tid == 0) row_ptr[n] = m;
}

__global__ void fill_kernel(const int* __restrict__ src, const int* __restrict__ dst,
                            const float* __restrict__ dinv, const int* __restrict__ row_ptr,
                            int* fill, int* __restrict__ col, float* __restrict__ wgt,
                            int e, int n) {
  int i = blockIdx.x * blockDim.x + threadIdx.x;
  if (i < e) {
    int s = src[i], d = dst[i];
    int pos = row_ptr[d] + atomicAdd(&fill[d], 1);
    col[pos] = s;
    wgt[pos] = dinv[s] * dinv[d];
  } else if (i < e + n) {
    int v = i - e;
    int pos = row_ptr[v] + atomicAdd(&fill[v], 1);
    col[pos] = v;
    float dv = dinv[v];
    wgt[pos] = dv * dv;
  }
}

// Build bf16 transposed weight mats + fp32 bias vectors for all 4 half-steps.
// WT[hsi][j][k] = W[g(j)][lay][k][j&63], g = half*4 + (j<64?0:2) + i (i=hsi>>1, half=hsi&1)
__global__ void prep_weights(const float* __restrict__ W, const float* __restrict__ B,
                             unsigned short* __restrict__ WT0, unsigned short* __restrict__ WT1,
                             float* __restrict__ b0c, float* __restrict__ b1c) {
  int idx = blockIdx.x * blockDim.x + threadIdx.x;
  if (idx < 65536) {
    int hsi = idx >> 14;
    int lay = (idx >> 13) & 1;
    int j = (idx >> 6) & 127;
    int k = idx & 63;
    int i = hsi >> 1, half = hsi & 1;
    int g = half * 4 + (j < 64 ? 0 : 2) + i;
    float v = W[(((size_t)g * 2 + lay) * 64 + k) * 64 + (j & 63)];
    unsigned short* dst = lay ? WT1 : WT0;
    dst[(size_t)hsi * 8192 + j * 64 + k] = f2bf(v);
  }
  if (idx < 1024) {
    int hsi = idx >> 8;
    int lay = (idx >> 7) & 1;
    int j = idx & 127;
    int i = hsi >> 1, half = hsi & 1;
    int g = half * 4 + (j < 64 ? 0 : 2) + i;
    (lay ? b1c : b0c)[hsi * 128 + j] = B[(g * 2 + lay) * 64 + (j & 63)];
  }
}

// Y[node] = sum_{edges into node} w * X[col].  Each lane owns a uint2 (4 bf16 feats).
// LPN lanes per node; 4-way unrolled -> 4 independent 8B gathers in flight.
template <int LPN>
__global__ void propagate_kernel(const unsigned int* __restrict__ X, int ldu, int xoffu,
                                 unsigned int* __restrict__ Y, int ldyu,
                                 const int* __restrict__ row_ptr, const int* __restrict__ col,
                                 const float* __restrict__ wgt, int n) {
  int t = blockIdx.x * blockDim.x + threadIdx.x;
  int node = t / LPN;
  int li = t % LPN;
  if (node >= n) return;
  int beg = row_ptr[node], end = row_ptr[node + 1];
  float a0 = 0.f, a1 = 0.f, a2 = 0.f, a3 = 0.f;
  int i = beg;
  for (; i + 4 <= end; i += 4) {
    int c0 = col[i], c1 = col[i + 1], c2 = col[i + 2], c3 = col[i + 3];
    float w0 = wgt[i], w1 = wgt[i + 1], w2 = wgt[i + 2], w3 = wgt[i + 3];
    uint2 u0 = *((const uint2*)(X + (size_t)c0 * ldu + xoffu) + li);
    uint2 u1 = *((const uint2*)(X + (size_t)c1 * ldu + xoffu) + li);
    uint2 u2 = *((const uint2*)(X + (size_t)c2 * ldu + xoffu) + li);
    uint2 u3 = *((const uint2*)(X + (size_t)c3 * ldu + xoffu) + li);
    a0 += w0 * bf_lo(u0.x); a1 += w0 * bf_hi(u0.x); a2 += w0 * bf_lo(u0.y); a3 += w0 * bf_hi(u0.y);
    a0 += w1 * bf_lo(u1.x); a1 += w1 * bf_hi(u1.x); a2 += w1 * bf_lo(u1.y); a3 += w1 * bf_hi(u1.y);
    a0 += w2 * bf_lo(u2.x); a1 += w2 * bf_hi(u2.x); a2 += w2 * bf_lo(u2.y); a3 += w2 * bf_hi(u2.y);
    a0 += w3 * bf_lo(u3.x); a1 += w3 * bf_hi(u3.x); a2 += w3 * bf_lo(u3.y); a3 += w3 * bf_hi(u3.y);
  }
  for (; i < end; ++i) {
    int c = col[i];
    float w = wgt[i];
    uint2 u = *((const uint2*)(X + (size_t)c * ldu + xoffu) + li);
    a0 += w * bf_lo(u.x); a1 += w * bf_hi(u.x); a2 += w * bf_lo(u.y); a3 += w * bf_hi(u.y);
  }
  uint2 r;
  r.x = pack2(a0, a1);
  r.y = pack2(a2, a3);
  *((uint2*)(Y + (size_t)node * ldyu) + li) = r;
}

// h1[r][j] = bf16(relu(p[r] @ Wcat0 + b0cat)), p:[n][64] bf16, Wcat0T:[128][64] bf16.
// Block = 64 rows (4 waves x 16). n % 16 == 0 so waves are all-or-nothing.
__global__ __launch_bounds__(256) void gemm_layer0(const unsigned short* __restrict__ P,
                                                   const unsigned short* __restrict__ WT,
                                                   const float* __restrict__ bc,
                                                   unsigned short* __restrict__ H1, int n) {
  int w = threadIdx.x >> 6, l = threadIdx.x & 63;
  int rbase = blockIdx.x * 64 + w * 16;
  if (rbase >= n) return;
  int lr = l & 15, kg = l >> 4;
  const bf16x8* ap = (const bf16x8*)(P + (size_t)(rbase + lr) * 64);
  bf16x8 a0 = ap[kg];      // k = kg*8
  bf16x8 a1 = ap[kg + 4];  // k = kg*8 + 32
  f32x4 acc[8];
#pragma unroll
  for (int ct = 0; ct < 8; ++ct) {
    const bf16x8* bp = (const bf16x8*)(WT + (size_t)(ct * 16 + lr) * 64);
    f32x4 c = {0.f, 0.f, 0.f, 0.f};
    c = __builtin_amdgcn_mfma_f32_16x16x32_bf16(a0, bp[kg], c, 0, 0, 0);
    c = __builtin_amdgcn_mfma_f32_16x16x32_bf16(a1, bp[kg + 4], c, 0, 0, 0);
    acc[ct] = c;
  }
#pragma unroll
  for (int ct = 0; ct < 8; ++ct) {
    int colj = ct * 16 + lr;
    float bb = bc[colj];
#pragma unroll
    for (int i2 = 0; i2 < 4; ++i2) {
      int row = rbase + kg * 4 + i2;  // C/D: col=lane&15, row=(lane>>4)*4+reg
      H1[(size_t)row * 128 + colj] = f2bf(fmaxf(acc[ct][i2] + bb, 0.f));
    }
  }
}

// s = sigmoid(q[:,:64]@Ws1+bs), t = sigmoid(q[:,64:]@Wt1+bt) via col-tile k-slicing;
// xout = xout*exp(s)+t (fp32 + bf16 mirror); ldj += sum(s).
__global__ __launch_bounds__(256) void gemm_final(const unsigned short* __restrict__ Q,
                                                  const unsigned short* __restrict__ WT,
                                                  const float* __restrict__ bc,
                                                  float* __restrict__ Xout,
                                                  unsigned short* __restrict__ Xb, int xoff,
                                                  float* __restrict__ ldj, int n) {
  int w = threadIdx.x >> 6, l = threadIdx.x & 63;
  int rbase = blockIdx.x * 64 + w * 16;
  if (rbase >= n) return;
  int lr = l & 15, kg = l >> 4;
  const bf16x8* ap = (const bf16x8*)(Q + (size_t)(rbase + lr) * 128);
  bf16x8 as0 = ap[kg], as1 = ap[kg + 4];    // k-slice [0,64)   for s (col-tiles 0-3)
  bf16x8 at0 = ap[kg + 8], at1 = ap[kg + 12];  // k-slice [64,128) for t (col-tiles 4-7)
  f32x4 acc[8];
#pragma unroll
  for (int ct = 0; ct < 8; ++ct) {
    const bf16x8* bp = (const bf16x8*)(WT + (size_t)(ct * 16 + lr) * 64);
    f32x4 c = {0.f, 0.f, 0.f, 0.f};
    bf16x8 x0 = (ct < 4) ? as0 : at0;
    bf16x8 x1 = (ct < 4) ? as1 : at1;
    c = __builtin_amdgcn_mfma_f32_16x16x32_bf16(x0, bp[kg], c, 0, 0, 0);
    c = __builtin_amdgcn_mfma_f32_16x16x32_bf16(x1, bp[kg + 4], c, 0, 0, 0);
    acc[ct] = c;
  }
  float wldj = 0.f;
#pragma unroll
  for (int ct = 0; ct < 4; ++ct) {
    int j = ct * 16 + lr;
    float bs = bc[j], bt = bc[j + 64];
#pragma unroll
    for (int i2 = 0; i2 < 4; ++i2) {
      int row = rbase + kg * 4 + i2;
      float sv = 1.f / (1.f + __expf(-(acc[ct][i2] + bs)));
      float tv = 1.f / (1.f + __expf(-(acc[ct + 4][i2] + bt)));
      size_t o = (size_t)row * 128 + xoff + j;
      float nv = Xout[o] * __expf(sv) + tv;
      Xout[o] = nv;
      Xb[o] = f2bf(nv);
      wldj += sv;
    }
  }
#pragma unroll
  for (int off2 = 32; off2 > 0; off2 >>= 1) wldj += __shfl_down(wldj, off2);
  if (l == 0) atomicAdd(ldj, wldj);
}

extern "C" void kernel_launch(void* const* d_in, const int* in_sizes, int n_in,
                              void* d_out, int out_size, void* d_ws, size_t ws_size,
                              hipStream_t stream) {
  const float* x = (const float*)d_in[0];
  const int* eidx = (const int*)d_in[1];
  const float* W = (const float*)d_in[2];
  const float* B = (const float*)d_in[3];
  float* out = (float*)d_out;

  int n = in_sizes[0] / 128;
  int e = in_sizes[1] / 2;
  int m = e + n;
  const int* src = eidx;
  const int* dstv = eidx + e;

  size_t off = 0;
  auto alloc = [&](size_t bytes) {
    size_t r = off;
    off += (bytes + 255) & ~(size_t)255;
    return r;
  };
  char* ws = (char*)d_ws;
  int* cnt = (int*)(ws + alloc((size_t)n * 4));
  int* fill = (int*)(ws + alloc((size_t)n * 4));
  int* row_ptr = (int*)(ws + alloc((size_t)(n + 1) * 4));
  float* dinv = (float*)(ws + alloc((size_t)n * 4));
  int* col = (int*)(ws + alloc((size_t)m * 4));
  float* wgt = (float*)(ws + alloc((size_t)m * 4));
  unsigned short* p = (unsigned short*)(ws + alloc((size_t)n * 64 * 2));    // bf16 A*x_in
  unsigned short* h1 = (unsigned short*)(ws + alloc((size_t)n * 128 * 2));  // bf16 hidden
  unsigned short* q = (unsigned short*)(ws + alloc((size_t)n * 128 * 2));   // bf16 A*h1
  unsigned short* xb = (unsigned short*)(ws + alloc((size_t)n * 128 * 2));  // bf16 state mirror
  unsigned short* wt0 = (unsigned short*)(ws + alloc((size_t)4 * 8192 * 2));
  unsigned short* wt1 = (unsigned short*)(ws + alloc((size_t)4 * 8192 * 2));
  float* b0c = (float*)(ws + alloc((size_t)4 * 128 * 4));
  float* b1c = (float*)(ws + alloc((size_t)4 * 128 * 4));

  int total = n * 128;
  init_out_kernel<<<(total + 256) / 256, 256, 0, stream>>>(x, out, xb, total);
  meta_init_kernel<<<(n + 255) / 256, 256, 0, stream>>>(cnt, fill, n);
  count_kernel<<<(e + 255) / 256, 256, 0, stream>>>(dstv, cnt, e);
  dinv_kernel<<<(n + 255) / 256, 256, 0, stream>>>(cnt, dinv, n);
  scan_kernel<<<1, 1024, 0, stream>>>(cnt, row_ptr, n, m);
  fill_kernel<<<(m + 255) / 256, 256, 0, stream>>>(src, dstv, dinv, row_ptr, fill, col, wgt, e, n);
  prep_weights<<<256, 256, 0, stream>>>(W, B, wt0, wt1, b0c, b1c);

  float* ldj = out + total;
  const int hs_xin[4] = {0, 64, 0, 64};
  int gblk = (n + 63) / 64;
  for (int hsi = 0; hsi < 4; ++hsi) {
    int xin = hs_xin[hsi];
    int xout = 64 - xin;
    // p = A * x_in (64 feats from bf16 mirror)
    propagate_kernel<16><<<(n * 16 + 255) / 256, 256, 0, stream>>>(
        (const unsigned int*)xb, 64, xin / 2, (unsigned int*)p, 32, row_ptr, col, wgt, n);
    gemm_layer0<<<gblk, 256, 0, stream>>>(p, wt0 + (size_t)hsi * 8192, b0c + hsi * 128, h1, n);
    // q = A * h1 (128 feats)
    propagate_kernel<32><<<(n * 32 + 255) / 256, 256, 0, stream>>>(
        (const unsigned int*)h1, 64, 0, (unsigned int*)q, 64, row_ptr, col, wgt, n);
    gemm_final<<<gblk, 256, 0, stream>>>(q, wt1 + (size_t)hsi * 8192, b1c + hsi * 128, out, xb,
                                         xout, ldj, n);
  }
}

// Round 4
// 603.683 us; speedup vs baseline: 3.0003x; 1.0815x over previous
//
#include <hip/hip_runtime.h>
#include <math.h>

// Graph normalizing flow on MI355X.
// State x (N x 128) fp32 lives in d_out; bf16 mirror xb for propagation gathers.
// ldj at d_out[N*128]. CSR-by-destination gather (no float atomics in hot path).
// A(hW)=(Ah)W rewrite: s/t GCN layer-0 share one 64-feat propagation.
// Dense layers are bf16 MFMA GEMMs with fused epilogues.
// Propagation: one WAVE per node (uniform edge-loop bounds), lanes = edge-slot x feat-chunk.

typedef __attribute__((ext_vector_type(8))) short bf16x8;
typedef __attribute__((ext_vector_type(4))) float f32x4;

__device__ __forceinline__ float bf_lo(unsigned int u) { return __uint_as_float(u << 16); }
__device__ __forceinline__ float bf_hi(unsigned int u) { return __uint_as_float(u & 0xffff0000u); }
__device__ __forceinline__ unsigned short f2bf(float f) {
  unsigned int u = __float_as_uint(f);
  u = (u + 0x7fffu + ((u >> 16) & 1u)) >> 16;  // round-to-nearest-even
  return (unsigned short)u;
}
__device__ __forceinline__ unsigned int pack2(float a, float b) {
  return (unsigned int)f2bf(a) | ((unsigned int)f2bf(b) << 16);
}

__global__ void init_out_kernel(const float* __restrict__ x, float* __restrict__ out,
                                unsigned short* __restrict__ xb, int total) {
  int i = blockIdx.x * blockDim.x + threadIdx.x;
  if (i < total) {
    float v = x[i];
    out[i] = v;
    xb[i] = f2bf(v);
  }
  if (i == 0) out[total] = 0.f;  // ldj accumulator
}

__global__ void meta_init_kernel(int* cnt, int* fill, int n) {
  int i = blockIdx.x * blockDim.x + threadIdx.x;
  if (i < n) { cnt[i] = 1; fill[i] = 0; }  // cnt starts at 1: self-loop
}

__global__ void count_kernel(const int* __restrict__ dst, int* cnt, int e) {
  int i = blockIdx.x * blockDim.x + threadIdx.x;
  if (i < e) atomicAdd(&cnt[dst[i]], 1);
}

__global__ void dinv_kernel(const int* __restrict__ cnt, float* __restrict__ dinv, int n) {
  int i = blockIdx.x * blockDim.x + threadIdx.x;
  if (i < n) dinv[i] = rsqrtf(fmaxf((float)cnt[i], 1.f));
}

// --- parallel exclusive scan: per-block scan -> scan block sums -> add offsets ---
__global__ void scan_blk_kernel(const int* __restrict__ cnt, int* __restrict__ row_ptr,
                                int* __restrict__ bsum, int n) {
  __shared__ int sdata[1024];
  int tid = threadIdx.x;
  int i = blockIdx.x * 1024 + tid;
  int v = (i < n) ? cnt[i] : 0;
  sdata[tid] = v;
  __syncthreads();
  for (int d = 1; d < 1024; d <<= 1) {
    int t = (tid >= d) ? sdata[tid - d] : 0;
    __syncthreads();
    sdata[tid] += t;
    __syncthreads();
  }
  if (i < n) row_ptr[i] = sdata[tid] - v;  // exclusive within block
  if (tid == 1023) bsum[blockIdx.x] = sdata[1023];
}

__global__ void scan_top_kernel(int* __restrict__ bsum, int nb) {
  __shared__ int sdata[1024];
  int tid = threadIdx.x;
  int v = (tid < nb) ? bsum[tid] : 0;
  sdata[tid] = v;
  __syncthreads();
  for (int d = 1; d < 1024; d <<= 1) {
    int t = (tid >= d) ? sdata[tid - d] : 0;
    __syncthreads();
    sdata[tid] += t;
    __syncthreads();
  }
  if (tid < nb) bsum[tid] = sdata[tid] - v;  // exclusive block offsets
}

__global__ void scan_add_kernel(int* __restrict__ row_ptr, const int* __restrict__ bsum,
                                int n, int m) {
  int i = blockIdx.x * blockDim.x + threadIdx.x;
  if (i < n) row_ptr[i] += bsum[i >> 10];
  if (i == 0) row_ptr[n] = m;
}

__global__ void fill_kernel(const int* __restrict__ src, const int* __restrict__ dst,
                            const float* __restrict__ dinv, const int* __restrict__ row_ptr,
                            int* fill, int* __restrict__ col, float* __restrict__ wgt,
                            int e, int n) {
  int i = blockIdx.x * blockDim.x + threadIdx.x;
  if (i < e) {
    int s = src[i], d = dst[i];
    int pos = row_ptr[d] + atomicAdd(&fill[d], 1);
    col[pos] = s;
    wgt[pos] = dinv[s] * dinv[d];
  } else if (i < e + n) {
    int v = i - e;
    int pos = row_ptr[v] + atomicAdd(&fill[v], 1);
    col[pos] = v;
    float dv = dinv[v];
    wgt[pos] = dv * dv;
  }
}

// Build bf16 transposed weight mats + fp32 bias vectors for all 4 half-steps.
__global__ void prep_weights(const float* __restrict__ W, const float* __restrict__ B,
                             unsigned short* __restrict__ WT0, unsigned short* __restrict__ WT1,
                             float* __restrict__ b0c, float* __restrict__ b1c) {
  int idx = blockIdx.x * blockDim.x + threadIdx.x;
  if (idx < 65536) {
    int hsi = idx >> 14;
    int lay = (idx >> 13) & 1;
    int j = (idx >> 6) & 127;
    int k = idx & 63;
    int i = hsi >> 1, half = hsi & 1;
    int g = half * 4 + (j < 64 ? 0 : 2) + i;
    float v = W[(((size_t)g * 2 + lay) * 64 + k) * 64 + (j & 63)];
    unsigned short* dst = lay ? WT1 : WT0;
    dst[(size_t)hsi * 8192 + j * 64 + k] = f2bf(v);
  }
  if (idx < 1024) {
    int hsi = idx >> 8;
    int lay = (idx >> 7) & 1;
    int j = idx & 127;
    int i = hsi >> 1, half = hsi & 1;
    int g = half * 4 + (j < 64 ? 0 : 2) + i;
    (lay ? b1c : b0c)[hsi * 128 + j] = B[(g * 2 + lay) * 64 + (j & 63)];
  }
}

// One wave per node. UPN = uint2-chunks per row (16 -> 64 feats, 32 -> 128 feats).
// Lanes: eo = edge slot (64/UPN slots), li = uint2 index. Wave-uniform loop bounds.
// 4-way edge unroll -> 4 independent 8B gathers in flight per thread.
template <int UPN>
__global__ void propagate_kernel(const unsigned int* __restrict__ X, int ldu, int xoffu,
                                 unsigned int* __restrict__ Y, int ldyu,
                                 const int* __restrict__ row_ptr, const int* __restrict__ col,
                                 const float* __restrict__ wgt, int n) {
  constexpr int EPG = 64 / UPN;  // edge slots per wave
  int wid = (blockIdx.x * blockDim.x + threadIdx.x) >> 6;
  if (wid >= n) return;
  int lane = threadIdx.x & 63;
  int eo = lane / UPN;
  int li = lane % UPN;
  int beg = row_ptr[wid], end = row_ptr[wid + 1];
  float a0 = 0.f, a1 = 0.f, a2 = 0.f, a3 = 0.f;
  int i = beg + eo;
  for (; i + 3 * EPG < end; i += 4 * EPG) {
    int c0 = col[i], c1 = col[i + EPG], c2 = col[i + 2 * EPG], c3 = col[i + 3 * EPG];
    float w0 = wgt[i], w1 = wgt[i + EPG], w2 = wgt[i + 2 * EPG], w3 = wgt[i + 3 * EPG];
    uint2 u0 = *((const uint2*)(X + (size_t)c0 * ldu + xoffu) + li);
    uint2 u1 = *((const uint2*)(X + (size_t)c1 * ldu + xoffu) + li);
    uint2 u2 = *((const uint2*)(X + (size_t)c2 * ldu + xoffu) + li);
    uint2 u3 = *((const uint2*)(X + (size_t)c3 * ldu + xoffu) + li);
    a0 += w0 * bf_lo(u0.x); a1 += w0 * bf_hi(u0.x); a2 += w0 * bf_lo(u0.y); a3 += w0 * bf_hi(u0.y);
    a0 += w1 * bf_lo(u1.x); a1 += w1 * bf_hi(u1.x); a2 += w1 * bf_lo(u1.y); a3 += w1 * bf_hi(u1.y);
    a0 += w2 * bf_lo(u2.x); a1 += w2 * bf_hi(u2.x); a2 += w2 * bf_lo(u2.y); a3 += w2 * bf_hi(u2.y);
    a0 += w3 * bf_lo(u3.x); a1 += w3 * bf_hi(u3.x); a2 += w3 * bf_lo(u3.y); a3 += w3 * bf_hi(u3.y);
  }
  for (; i < end; i += EPG) {
    int c = col[i];
    float w = wgt[i];
    uint2 u = *((const uint2*)(X + (size_t)c * ldu + xoffu) + li);
    a0 += w * bf_lo(u.x); a1 += w * bf_hi(u.x); a2 += w * bf_lo(u.y); a3 += w * bf_hi(u.y);
  }
  // reduce across edge slots (lanes differing in bits >= log2(UPN))
#pragma unroll
  for (int ms = UPN; ms < 64; ms <<= 1) {
    a0 += __shfl_xor(a0, ms);
    a1 += __shfl_xor(a1, ms);
    a2 += __shfl_xor(a2, ms);
    a3 += __shfl_xor(a3, ms);
  }
  if (lane < UPN) {
    uint2 r;
    r.x = pack2(a0, a1);
    r.y = pack2(a2, a3);
    *((uint2*)(Y + (size_t)wid * ldyu) + li) = r;
  }
}

// h1[r][j] = bf16(relu(p[r] @ Wcat0 + b0cat)), p:[n][64] bf16, WT:[128][64] bf16.
__global__ __launch_bounds__(256) void gemm_layer0(const unsigned short* __restrict__ P,
                                                   const unsigned short* __restrict__ WT,
                                                   const float* __restrict__ bc,
                                                   unsigned short* __restrict__ H1, int n) {
  int w = threadIdx.x >> 6, l = threadIdx.x & 63;
  int rbase = blockIdx.x * 64 + w * 16;
  if (rbase >= n) return;
  int lr = l & 15, kg = l >> 4;
  const bf16x8* ap = (const bf16x8*)(P + (size_t)(rbase + lr) * 64);
  bf16x8 a0 = ap[kg];
  bf16x8 a1 = ap[kg + 4];
  f32x4 acc[8];
#pragma unroll
  for (int ct = 0; ct < 8; ++ct) {
    const bf16x8* bp = (const bf16x8*)(WT + (size_t)(ct * 16 + lr) * 64);
    f32x4 c = {0.f, 0.f, 0.f, 0.f};
    c = __builtin_amdgcn_mfma_f32_16x16x32_bf16(a0, bp[kg], c, 0, 0, 0);
    c = __builtin_amdgcn_mfma_f32_16x16x32_bf16(a1, bp[kg + 4], c, 0, 0, 0);
    acc[ct] = c;
  }
#pragma unroll
  for (int ct = 0; ct < 8; ++ct) {
    int colj = ct * 16 + lr;
    float bb = bc[colj];
#pragma unroll
    for (int i2 = 0; i2 < 4; ++i2) {
      int row = rbase + kg * 4 + i2;  // C/D: col=lane&15, row=(lane>>4)*4+reg
      H1[(size_t)row * 128 + colj] = f2bf(fmaxf(acc[ct][i2] + bb, 0.f));
    }
  }
}

// s = sigmoid(q[:,:64]@Ws1+bs), t = sigmoid(q[:,64:]@Wt1+bt); xout=xout*exp(s)+t; ldj+=sum(s)
__global__ __launch_bounds__(256) void gemm_final(const unsigned short* __restrict__ Q,
                                                  const unsigned short* __restrict__ WT,
                                                  const float* __restrict__ bc,
                                                  float* __restrict__ Xout,
                                                  unsigned short* __restrict__ Xb, int xoff,
                                                  float* __restrict__ ldj, int n) {
  int w = threadIdx.x >> 6, l = threadIdx.x & 63;
  int rbase = blockIdx.x * 64 + w * 16;
  if (rbase >= n) return;
  int lr = l & 15, kg = l >> 4;
  const bf16x8* ap = (const bf16x8*)(Q + (size_t)(rbase + lr) * 128);
  bf16x8 as0 = ap[kg], as1 = ap[kg + 4];
  bf16x8 at0 = ap[kg + 8], at1 = ap[kg + 12];
  f32x4 acc[8];
#pragma unroll
  for (int ct = 0; ct < 8; ++ct) {
    const bf16x8* bp = (const bf16x8*)(WT + (size_t)(ct * 16 + lr) * 64);
    f32x4 c = {0.f, 0.f, 0.f, 0.f};
    bf16x8 x0 = (ct < 4) ? as0 : at0;
    bf16x8 x1 = (ct < 4) ? as1 : at1;
    c = __builtin_amdgcn_mfma_f32_16x16x32_bf16(x0, bp[kg], c, 0, 0, 0);
    c = __builtin_amdgcn_mfma_f32_16x16x32_bf16(x1, bp[kg + 4], c, 0, 0, 0);
    acc[ct] = c;
  }
  float wldj = 0.f;
#pragma unroll
  for (int ct = 0; ct < 4; ++ct) {
    int j = ct * 16 + lr;
    float bs = bc[j], bt = bc[j + 64];
#pragma unroll
    for (int i2 = 0; i2 < 4; ++i2) {
      int row = rbase + kg * 4 + i2;
      float sv = 1.f / (1.f + __expf(-(acc[ct][i2] + bs)));
      float tv = 1.f / (1.f + __expf(-(acc[ct + 4][i2] + bt)));
      size_t o = (size_t)row * 128 + xoff + j;
      float nv = Xout[o] * __expf(sv) + tv;
      Xout[o] = nv;
      Xb[o] = f2bf(nv);
      wldj += sv;
    }
  }
#pragma unroll
  for (int off2 = 32; off2 > 0; off2 >>= 1) wldj += __shfl_down(wldj, off2);
  if (l == 0) atomicAdd(ldj, wldj);
}

extern "C" void kernel_launch(void* const* d_in, const int* in_sizes, int n_in,
                              void* d_out, int out_size, void* d_ws, size_t ws_size,
                              hipStream_t stream) {
  const float* x = (const float*)d_in[0];
  const int* eidx = (const int*)d_in[1];
  const float* W = (const float*)d_in[2];
  const float* B = (const float*)d_in[3];
  float* out = (float*)d_out;

  int n = in_sizes[0] / 128;
  int e = in_sizes[1] / 2;
  int m = e + n;
  const int* src = eidx;
  const int* dstv = eidx + e;

  size_t off = 0;
  auto alloc = [&](size_t bytes) {
    size_t r = off;
    off += (bytes + 255) & ~(size_t)255;
    return r;
  };
  char* ws = (char*)d_ws;
  int* cnt = (int*)(ws + alloc((size_t)n * 4));
  int* fill = (int*)(ws + alloc((size_t)n * 4));
  int* row_ptr = (int*)(ws + alloc((size_t)(n + 1) * 4));
  int* bsum = (int*)(ws + alloc((size_t)1024 * 4));
  float* dinv = (float*)(ws + alloc((size_t)n * 4));
  int* col = (int*)(ws + alloc((size_t)m * 4));
  float* wgt = (float*)(ws + alloc((size_t)m * 4));
  unsigned short* p = (unsigned short*)(ws + alloc((size_t)n * 64 * 2));    // bf16 A*x_in
  unsigned short* h1 = (unsigned short*)(ws + alloc((size_t)n * 128 * 2));  // bf16 hidden
  unsigned short* q = (unsigned short*)(ws + alloc((size_t)n * 128 * 2));   // bf16 A*h1
  unsigned short* xb = (unsigned short*)(ws + alloc((size_t)n * 128 * 2));  // bf16 state mirror
  unsigned short* wt0 = (unsigned short*)(ws + alloc((size_t)4 * 8192 * 2));
  unsigned short* wt1 = (unsigned short*)(ws + alloc((size_t)4 * 8192 * 2));
  float* b0c = (float*)(ws + alloc((size_t)4 * 128 * 4));
  float* b1c = (float*)(ws + alloc((size_t)4 * 128 * 4));

  int total = n * 128;
  int nb = (n + 1023) / 1024;
  init_out_kernel<<<(total + 256) / 256, 256, 0, stream>>>(x, out, xb, total);
  meta_init_kernel<<<(n + 255) / 256, 256, 0, stream>>>(cnt, fill, n);
  count_kernel<<<(e + 255) / 256, 256, 0, stream>>>(dstv, cnt, e);
  dinv_kernel<<<(n + 255) / 256, 256, 0, stream>>>(cnt, dinv, n);
  scan_blk_kernel<<<nb, 1024, 0, stream>>>(cnt, row_ptr, bsum, n);
  scan_top_kernel<<<1, 1024, 0, stream>>>(bsum, nb);
  scan_add_kernel<<<(n + 255) / 256, 256, 0, stream>>>(row_ptr, bsum, n, m);
  fill_kernel<<<(m + 255) / 256, 256, 0, stream>>>(src, dstv, dinv, row_ptr, fill, col, wgt, e, n);
  prep_weights<<<256, 256, 0, stream>>>(W, B, wt0, wt1, b0c, b1c);

  float* ldj = out + total;
  const int hs_xin[4] = {0, 64, 0, 64};
  int gblk = (n + 63) / 64;
  int pgrid = (n * 64 + 255) / 256;  // one wave per node
  for (int hsi = 0; hsi < 4; ++hsi) {
    int xin = hs_xin[hsi];
    int xout = 64 - xin;
    // p = A * x_in (64 feats from bf16 mirror)
    propagate_kernel<16><<<pgrid, 256, 0, stream>>>(
        (const unsigned int*)xb, 64, xin / 2, (unsigned int*)p, 32, row_ptr, col, wgt, n);
    gemm_layer0<<<gblk, 256, 0, stream>>>(p, wt0 + (size_t)hsi * 8192, b0c + hsi * 128, h1, n);
    // q = A * h1 (128 feats)
    propagate_kernel<32><<<pgrid, 256, 0, stream>>>(
        (const unsigned int*)h1, 64, 0, (unsigned int*)q, 64, row_ptr, col, wgt, n);
    gemm_final<<<gblk, 256, 0, stream>>>(q, wt1 + (size_t)hsi * 8192, b1c + hsi * 128, out, xb,
                                         xout, ldj, n);
  }
}